// Round 2
// baseline (572.916 us; speedup 1.0000x reference)
//
#include <hip/hip_runtime.h>

#define NB 16
#define NH 128
#define NW 128
#define NC 64   // in channels
#define NO 64   // out channels
#define NM 16   // modes

// workspace float offsets (all multiples of 4 -> 16B aligned)
#define OFF_TW   0                          // 256 floats (cos,sin)[128]
#define OFF_WTR  1024                       // 1048576: Wt_re[kk][i][o]
#define OFF_WTI  (OFF_WTR + 1048576)
#define OFF_AR   (OFF_WTI + 1048576)        // 2097152: T1_re[b][ky][h][i] / T2_re[b][h][ky][o]
#define OFF_AI   (OFF_AR + 2097152)
#define OFF_XR   (OFF_AI + 2097152)         // 262144: X_re[kk][b][i]
#define OFF_XI   (OFF_XR + 262144)
#define OFF_OR   (OFF_XI + 262144)          // 262144: O_re[kk][b][o]
#define OFF_OI   (OFF_OR + 262144)

#define R2F 0.70710678118654752f

// cos(pi*t/64) for t=0..32 (standard 128-pt twiddle quarter table)
constexpr float CQ[33] = {
  1.000000000f, 0.998795456f, 0.995184727f, 0.989176510f,
  0.980785280f, 0.970031253f, 0.956940336f, 0.941544065f,
  0.923879533f, 0.903989293f, 0.881921264f, 0.857728610f,
  0.831469612f, 0.803207531f, 0.773010453f, 0.740951125f,
  0.707106781f, 0.671558955f, 0.634393284f, 0.595699304f,
  0.555570233f, 0.514102744f, 0.471396737f, 0.427555093f,
  0.382683432f, 0.336889853f, 0.290284677f, 0.242980180f,
  0.195090322f, 0.146730474f, 0.098017140f, 0.049067674f,
  0.000000000f };

__host__ __device__ constexpr float twcos(int t) {   // cos(2*pi*t/128)
  t &= 127;
  return (t <= 32) ? CQ[t] : (t < 64) ? -CQ[64 - t] : (t <= 96) ? -CQ[t - 64] : CQ[128 - t];
}
__host__ __device__ constexpr float twsin(int t) { return twcos(t + 96); }  // sin(2*pi*t/128)

// acc += (gr + i*gi) * e^{-2*pi*i*t/128}   (t folds to literal under full unroll)
__device__ __forceinline__ void caccN(int t, float gr, float gi, float& ar, float& ai) {
  t &= 127;
  if (t == 0)       { ar += gr; ai += gi; }
  else if (t == 64) { ar -= gr; ai -= gi; }
  else if (t == 32) { ar += gi; ai -= gr; }    // * (-i)
  else if (t == 96) { ar -= gi; ai += gr; }    // * (+i)
  else {
    const float c = twcos(t), s = twsin(t);
    ar = fmaf(gr, c, fmaf(gi, s, ar));
    ai = fmaf(gi, c, fmaf(-gr, s, ai));
  }
}
// acc += (gr + i*gi) * e^{+2*pi*i*t/128}
__device__ __forceinline__ void caccP(int t, float gr, float gi, float& ar, float& ai) {
  t &= 127;
  if (t == 0)       { ar += gr; ai += gi; }
  else if (t == 64) { ar -= gr; ai -= gi; }
  else if (t == 32) { ar -= gi; ai += gr; }    // * (+i)
  else if (t == 96) { ar += gi; ai -= gr; }    // * (-i)
  else {
    const float c = twcos(t), s = twsin(t);
    ar = fmaf(gr, c, fmaf(-gi, s, ar));
    ai = fmaf(gi, c, fmaf(gr, s, ai));
  }
}
// acc += x * e^{-2*pi*i*t/128}  (real input)
__device__ __forceinline__ void raccN(int t, float x, float& ar, float& ai) {
  t &= 127;
  if (t == 0)       { ar += x; }
  else if (t == 64) { ar -= x; }
  else if (t == 32) { ai -= x; }
  else if (t == 96) { ai += x; }
  else {
    ar = fmaf(x, twcos(t), ar);
    ai = fmaf(x, -twsin(t), ai);
  }
}

// ------------------------------------------------- weight transpose (+ twiddle table for k3)
__global__ __launch_bounds__(256) void k_wt(const float* __restrict__ wre,
                                            const float* __restrict__ wim,
                                            float* __restrict__ wtr,
                                            float* __restrict__ wti,
                                            float* __restrict__ tw) {
  if (blockIdx.x == 0 && threadIdx.x < 128) {
    const int t = threadIdx.x;
    const float ang = 6.2831853071795864769f * (float)t / 128.0f;
    tw[2 * t]     = cosf(ang);
    tw[2 * t + 1] = sinf(ang);
  }
  __shared__ float buf[64 * 257];  // [o][kk] padded
  const int i = blockIdx.x & 63;
  const float* src = (blockIdx.x < 64) ? wre : wim;
  float* dst       = (blockIdx.x < 64) ? wtr : wti;
  const float* s = src + (size_t)i * 16384;
  for (int t = threadIdx.x; t < 16384; t += 256) {
    int o = t >> 8, kk = t & 255;
    buf[o * 257 + kk] = s[t];
  }
  __syncthreads();
  for (int t = threadIdx.x; t < 16384; t += 256) {
    int kk = t >> 6, o = t & 63;
    dst[(size_t)kk * 4096 + i * 64 + o] = buf[o * 257 + kk];
  }
}

// ---------------------------------------------------------------- K1: w-DFT (radix 16x8, literal twiddles)
// T1[b][ky][h][i] = sum_w x[b,h,w,i] * e^{-2pi i ky w/128}
__global__ __launch_bounds__(256) void k1_wdft(const float* __restrict__ x,
                                               float* __restrict__ t1r,
                                               float* __restrict__ t1i) {
  const int wid  = threadIdx.x >> 6;
  const int lane = threadIdx.x & 63;            // i
  const int slab = blockIdx.x * 4 + wid;        // b*128 + h
  const float* xp = x + (size_t)slab * (NW * NC) + lane;
  float Tr[NM], Ti[NM];
#pragma unroll
  for (int k = 0; k < NM; ++k) { Tr[k] = 0.f; Ti[k] = 0.f; }
#pragma unroll
  for (int w0 = 0; w0 < 16; ++w0) {
    float xv[8];
#pragma unroll
    for (int w1 = 0; w1 < 8; ++w1) xv[w1] = xp[(size_t)(w1 * 16 + w0) * NC];
    // 8-point real-input DFT (w1 axis), twiddles are exact constants
    const float s0 = xv[0] + xv[4], d0 = xv[0] - xv[4];
    const float s1 = xv[1] + xv[5], d1 = xv[1] - xv[5];
    const float s2 = xv[2] + xv[6], d2 = xv[2] - xv[6];
    const float s3 = xv[3] + xv[7], d3 = xv[3] - xv[7];
    const float e0 = s0 + s2, e1 = s0 - s2;
    const float f0 = s1 + s3, f1 = s1 - s3;
    const float u = R2F * (d1 - d3), v = R2F * (d1 + d3);
    const float g0r = e0 + f0;                 // G0 (real)
    const float g4r = e0 - f0;                 // G4 (real)
    const float g1r = d0 + u, g1i = -(d2 + v); // G1
    const float g2r = e1,     g2i = -f1;       // G2
    const float g3r = d0 - u, g3i = d2 - v;    // G3; G5..7 = conj(G3..1)
#pragma unroll
    for (int ky = 0; ky < 16; ++ky) {
      const int p = ky & 7;
      const int t = ky * w0;
      if      (p == 0) raccN(t, g0r, Tr[ky], Ti[ky]);
      else if (p == 4) raccN(t, g4r, Tr[ky], Ti[ky]);
      else if (p == 1) caccN(t, g1r,  g1i, Tr[ky], Ti[ky]);
      else if (p == 2) caccN(t, g2r,  g2i, Tr[ky], Ti[ky]);
      else if (p == 3) caccN(t, g3r,  g3i, Tr[ky], Ti[ky]);
      else if (p == 5) caccN(t, g3r, -g3i, Tr[ky], Ti[ky]);
      else if (p == 6) caccN(t, g2r, -g2i, Tr[ky], Ti[ky]);
      else             caccN(t, g1r, -g1i, Tr[ky], Ti[ky]);
    }
  }
  const int b = slab >> 7, h = slab & 127;
#pragma unroll
  for (int ky = 0; ky < NM; ++ky) {
    const size_t idx = (((size_t)(b * NM + ky)) * NH + h) * NC + lane;
    t1r[idx] = Tr[ky];
    t1i[idx] = Ti[ky];
  }
}

// ---------------------------------------------------------------- K2a: h-DFT (literal twiddles)
// X[kk=(kx*16+ky)][b][i] = sum_h T1[b][ky][h][i] * e^{-2pi i kx h/128}
__global__ __launch_bounds__(256) void k2a_hdft(const float* __restrict__ t1r,
                                               const float* __restrict__ t1i,
                                               float* __restrict__ xre,
                                               float* __restrict__ xim) {
  __shared__ float lpr[4][NM][64];
  __shared__ float lpi[4][NM][64];
  const int bk   = blockIdx.x;                  // b*16 + ky
  const int hq   = threadIdx.x >> 6;
  const int lane = threadIdx.x & 63;            // i
  const float* pr = t1r + (size_t)bk * (NH * NC) + (size_t)hq * 32 * NC + lane;
  const float* pi = t1i + (size_t)bk * (NH * NC) + (size_t)hq * 32 * NC + lane;
  float xr[NM], xv[NM];
#pragma unroll
  for (int k = 0; k < NM; ++k) { xr[k] = 0.f; xv[k] = 0.f; }
#pragma unroll
  for (int hh = 0; hh < 32; ++hh) {
    const float re = pr[(size_t)hh * NC];
    const float im = pi[(size_t)hh * NC];
#pragma unroll
    for (int kx = 0; kx < 16; ++kx) caccN(kx * hh, re, im, xr[kx], xv[kx]);
  }
  // post-rotate by (-i)^{kx*hq}   (h = 32*hq + hh)
  if (hq == 1) {
#pragma unroll
    for (int kx = 0; kx < 16; ++kx) {
      const int m = kx & 3;
      const float r = xr[kx], im = xv[kx];
      if      (m == 1) { xr[kx] = im;  xv[kx] = -r; }
      else if (m == 2) { xr[kx] = -r;  xv[kx] = -im; }
      else if (m == 3) { xr[kx] = -im; xv[kx] = r; }
    }
  } else if (hq == 2) {
#pragma unroll
    for (int kx = 0; kx < 16; ++kx) {
      if (kx & 1) { xr[kx] = -xr[kx]; xv[kx] = -xv[kx]; }
    }
  } else if (hq == 3) {   // (-i)^{3kx} = i^{kx}
#pragma unroll
    for (int kx = 0; kx < 16; ++kx) {
      const int m = kx & 3;
      const float r = xr[kx], im = xv[kx];
      if      (m == 1) { xr[kx] = -im; xv[kx] = r; }
      else if (m == 2) { xr[kx] = -r;  xv[kx] = -im; }
      else if (m == 3) { xr[kx] = im;  xv[kx] = -r; }
    }
  }
#pragma unroll
  for (int kx = 0; kx < 16; ++kx) {
    lpr[hq][kx][lane] = xr[kx];
    lpi[hq][kx][lane] = xv[kx];
  }
  __syncthreads();
  const int i  = threadIdx.x & 63;
  const int kq = threadIdx.x >> 6;
  const int b = bk >> 4, ky = bk & 15;
#pragma unroll
  for (int p = 0; p < 4; ++p) {
    const int kx = kq * 4 + p;
    const float sr = lpr[0][kx][i] + lpr[1][kx][i] + lpr[2][kx][i] + lpr[3][kx][i];
    const float si = lpi[0][kx][i] + lpi[1][kx][i] + lpi[2][kx][i] + lpi[3][kx][i];
    const size_t idx = ((size_t)(kx * NM + ky)) * (NB * NC) + b * NC + i;
    xre[idx] = sr;
    xim[idx] = si;
  }
}

// ---------------------------------------------------------------- K2b: channel mix per mode (unchanged)
__global__ __launch_bounds__(256) void k2b_mix(const float* __restrict__ xre,
                                              const float* __restrict__ xim,
                                              const float* __restrict__ wtr,
                                              const float* __restrict__ wti,
                                              float* __restrict__ ore,
                                              float* __restrict__ oim) {
  __shared__ __align__(16) float lwr[4096], lwi[4096];  // [i][o]
  __shared__ __align__(16) float lxr[1024], lxi[1024];  // [b][i]
  const int kk = blockIdx.x;
  for (int t = threadIdx.x; t < 4096; t += 256) {
    lwr[t] = wtr[(size_t)kk * 4096 + t];
    lwi[t] = wti[(size_t)kk * 4096 + t];
  }
  for (int t = threadIdx.x; t < 1024; t += 256) {
    lxr[t] = xre[(size_t)kk * 1024 + t];
    lxi[t] = xim[(size_t)kk * 1024 + t];
  }
  __syncthreads();
  const int o  = threadIdx.x & 63;
  const int bq = threadIdx.x >> 6;
  float accr[4] = {0, 0, 0, 0}, acci[4] = {0, 0, 0, 0};
  for (int iq = 0; iq < 16; ++iq) {
    float xrv[4][4], xiv[4][4];
#pragma unroll
    for (int p = 0; p < 4; ++p) {
      const int b = bq * 4 + p;
      float4 vr = ((const float4*)lxr)[b * 16 + iq];
      float4 vi = ((const float4*)lxi)[b * 16 + iq];
      xrv[p][0] = vr.x; xrv[p][1] = vr.y; xrv[p][2] = vr.z; xrv[p][3] = vr.w;
      xiv[p][0] = vi.x; xiv[p][1] = vi.y; xiv[p][2] = vi.z; xiv[p][3] = vi.w;
    }
#pragma unroll
    for (int j = 0; j < 4; ++j) {
      const int i2 = iq * 4 + j;
      const float wr = lwr[i2 * 64 + o];
      const float wi = lwi[i2 * 64 + o];
#pragma unroll
      for (int p = 0; p < 4; ++p) {
        accr[p] = fmaf(xrv[p][j], wr, fmaf(-xiv[p][j], wi, accr[p]));
        acci[p] = fmaf(xrv[p][j], wi, fmaf(xiv[p][j], wr, acci[p]));
      }
    }
  }
#pragma unroll
  for (int p = 0; p < 4; ++p) {
    const int b = bq * 4 + p;
    ore[(size_t)kk * 1024 + b * 64 + o] = accr[p];
    oim[(size_t)kk * 1024 + b * 64 + o] = acci[p];
  }
}

// ---------------------------------------------------------------- K3: h-inverse, T2 layout [b][h][ky][o]
// T2[b][h][ky][o] = cfac(ky)/16384 * sum_kx O[kx*16+ky][b][o] * e^{+2pi i kx h/128}
// grid 512 = (b, hq in [0,32)), h = 4*hq + j; wave q owns ky in [4q,4q+4); lane = o.
__global__ __launch_bounds__(256) void k3_hidft(const float* __restrict__ ore,
                                               const float* __restrict__ oim,
                                               const float* __restrict__ tw,
                                               float* __restrict__ t2r,
                                               float* __restrict__ t2i) {
  const int b = blockIdx.x >> 5, hq = blockIdx.x & 31;
  const int q = threadIdx.x >> 6, lane = threadIdx.x & 63;
  const int ky0 = q * 4;
  float tr[4][4], ti[4][4];                      // [j(h)][ky]
#pragma unroll
  for (int j = 0; j < 4; ++j)
#pragma unroll
    for (int k = 0; k < 4; ++k) { tr[j][k] = 0.f; ti[j][k] = 0.f; }
  const size_t obase = (size_t)b * 64 + lane;
  for (int kx = 0; kx < 16; ++kx) {
    float c[4], s[4];
#pragma unroll
    for (int j = 0; j < 4; ++j) {                // block-uniform index -> scalar loads
      const int t = (kx * (hq * 4 + j)) & 127;
      c[j] = tw[2 * t];
      s[j] = tw[2 * t + 1];
    }
    float orv[4], oiv[4];
#pragma unroll
    for (int k = 0; k < 4; ++k) {
      const size_t idx = (size_t)(kx * 16 + ky0 + k) * (NB * NO) + obase;
      orv[k] = ore[idx];
      oiv[k] = oim[idx];
    }
#pragma unroll
    for (int j = 0; j < 4; ++j)
#pragma unroll
      for (int k = 0; k < 4; ++k) {
        tr[j][k] = fmaf(orv[k], c[j], fmaf(-oiv[k], s[j], tr[j][k]));
        ti[j][k] = fmaf(orv[k], s[j], fmaf( oiv[k], c[j], ti[j][k]));
      }
  }
#pragma unroll
  for (int j = 0; j < 4; ++j) {
    const int h = hq * 4 + j;
#pragma unroll
    for (int k = 0; k < 4; ++k) {
      const int ky = ky0 + k;
      const float sc = (ky == 0 ? 1.0f : 2.0f) * (1.0f / 16384.0f);
      const size_t idx = ((size_t)(b * NH + h) * NM + ky) * NO + lane;
      t2r[idx] = tr[j][k] * sc;
      t2i[idx] = ti[j][k] * sc;
    }
  }
}

// ---------------------------------------------------------------- K5: w-inverse (radix, literal twiddles)
// y[b,h,w,o] = Re sum_ky T2[b][h][ky][o] * e^{+2pi i ky w/128}
__global__ __launch_bounds__(256) void k5_widft(const float* __restrict__ t2r,
                                               const float* __restrict__ t2i,
                                               float* __restrict__ y) {
  const int wid  = threadIdx.x >> 6;
  const int lane = threadIdx.x & 63;            // o
  const int slab = blockIdx.x * 4 + wid;        // b*128 + h
  const float* pr = t2r + (size_t)slab * (NM * NO) + lane;
  const float* pi = t2i + (size_t)slab * (NM * NO) + lane;
  float Tr[NM], Ti[NM];
#pragma unroll
  for (int ky = 0; ky < NM; ++ky) {
    Tr[ky] = pr[ky * NO];
    Ti[ky] = pi[ky * NO];
  }
  float* yp = y + (size_t)slab * (NW * NO) + lane;
#pragma unroll
  for (int w0 = 0; w0 < 16; ++w0) {
    // U_p = sum_{ky: ky&7==p} T[ky] * e^{+2pi i ky w0/128}
    float Ur[8], Ui[8];
#pragma unroll
    for (int p = 0; p < 8; ++p) { Ur[p] = 0.f; Ui[p] = 0.f; }
#pragma unroll
    for (int ky = 0; ky < 16; ++ky) caccP(ky * w0, Tr[ky], Ti[ky], Ur[ky & 7], Ui[ky & 7]);
    // y[16*w1+w0] = Re( sum_p U_p e^{+2pi i p w1/8} ) -- 8-pt real-part butterfly
    const float A  = Ur[0], B = Ur[4];
    const float Cr = Ur[2] + Ur[6], Ci = Ui[2] - Ui[6];
    const float Dr = Ur[1] + Ur[7], Di = Ui[1] - Ui[7];
    const float Er = Ur[3] + Ur[5], Ei = Ui[3] - Ui[5];
    const float P = A + B, M = A - B;
    const float DE = Dr + Er, IE = Di - Ei;
    const float X1 = R2F * ((Dr - Di) - (Er + Ei));
    const float X3 = R2F * ((Dr + Di) - (Er - Ei));
    const float MmC = M - Ci, MpC = M + Ci, PpC = P + Cr, PmC = P - Cr;
    float yv[8];
    yv[0] = PpC + DE;  yv[4] = PpC - DE;
    yv[2] = PmC - IE;  yv[6] = PmC + IE;
    yv[1] = MmC + X1;  yv[5] = MmC - X1;
    yv[3] = MpC - X3;  yv[7] = MpC + X3;
#pragma unroll
    for (int w1 = 0; w1 < 8; ++w1) yp[(size_t)(w1 * 16 + w0) * NO] = yv[w1];
  }
}

extern "C" void kernel_launch(void* const* d_in, const int* in_sizes, int n_in,
                              void* d_out, int out_size, void* d_ws, size_t ws_size,
                              hipStream_t stream) {
  const float* x   = (const float*)d_in[0];
  const float* wre = (const float*)d_in[1];
  const float* wim = (const float*)d_in[2];
  float* ws  = (float*)d_ws;
  float* tw  = ws + OFF_TW;
  float* wtr = ws + OFF_WTR;
  float* wti = ws + OFF_WTI;
  float* ar  = ws + OFF_AR;   // T1, later T2 (re)
  float* ai  = ws + OFF_AI;   // T1, later T2 (im)
  float* xr  = ws + OFF_XR;
  float* xi  = ws + OFF_XI;
  float* orr = ws + OFF_OR;
  float* oii = ws + OFF_OI;
  float* y   = (float*)d_out;

  k_wt<<<128, 256, 0, stream>>>(wre, wim, wtr, wti, tw);
  k1_wdft<<<512, 256, 0, stream>>>(x, ar, ai);
  k2a_hdft<<<NB * NM, 256, 0, stream>>>(ar, ai, xr, xi);
  k2b_mix<<<NM * NM, 256, 0, stream>>>(xr, xi, wtr, wti, orr, oii);
  k3_hidft<<<512, 256, 0, stream>>>(orr, oii, tw, ar, ai);   // ar/ai now hold T2[b][h][ky][o]
  k5_widft<<<512, 256, 0, stream>>>(ar, ai, y);
}

// Round 3
// 168.872 us; speedup vs baseline: 3.3926x; 3.3926x over previous
//
#include <hip/hip_runtime.h>

#define NB 16
#define NH 128
#define NW 128
#define NC 64   // in channels
#define NO 64   // out channels
#define NM 16   // modes

// workspace float offsets
#define OFF_WTR  0                          // 1048576: Wt_re[kk][i][o]
#define OFF_WTI  (OFF_WTR + 1048576)
#define OFF_AR   (OFF_WTI + 1048576)        // 2097152: T1_re[b][ky][h][i] / T2_re[b][h][ky][o]
#define OFF_AI   (OFF_AR + 2097152)
#define OFF_XR   (OFF_AI + 2097152)         // 262144: X_re[kk][b][i]
#define OFF_XI   (OFF_XR + 262144)
#define OFF_OR   (OFF_XI + 262144)          // 262144: O_re[kk][b][o]
#define OFF_OI   (OFF_OR + 262144)

#define R2F 0.70710678118654752f

// cos(pi*t/64) for t=0..32
constexpr float CQ[33] = {
  1.000000000f, 0.998795456f, 0.995184727f, 0.989176510f,
  0.980785280f, 0.970031253f, 0.956940336f, 0.941544065f,
  0.923879533f, 0.903989293f, 0.881921264f, 0.857728610f,
  0.831469612f, 0.803207531f, 0.773010453f, 0.740951125f,
  0.707106781f, 0.671558955f, 0.634393284f, 0.595699304f,
  0.555570233f, 0.514102744f, 0.471396737f, 0.427555093f,
  0.382683432f, 0.336889853f, 0.290284677f, 0.242980180f,
  0.195090322f, 0.146730474f, 0.098017140f, 0.049067674f,
  0.000000000f };

__host__ __device__ constexpr float twcos(int t) {   // cos(2*pi*t/128)
  t &= 127;
  return (t <= 32) ? CQ[t] : (t < 64) ? -CQ[64 - t] : (t <= 96) ? -CQ[t - 64] : CQ[128 - t];
}
__host__ __device__ constexpr float twsin(int t) { return twcos(t + 96); }

// ---- template twiddle ops: T is a compile-time exponent; folding guaranteed ----
// acc += (gr + i gi) * e^{-2 pi i T/128}
template<int T>
__device__ __forceinline__ void caccN_t(float gr, float gi, float& ar, float& ai) {
  constexpr int t = T & 127;
  if constexpr (t == 0)       { ar += gr; ai += gi; }
  else if constexpr (t == 64) { ar -= gr; ai -= gi; }
  else if constexpr (t == 32) { ar += gi; ai -= gr; }
  else if constexpr (t == 96) { ar -= gi; ai += gr; }
  else {
    constexpr float c = twcos(t), s = twsin(t);
    ar = fmaf(gr, c, fmaf(gi, s, ar));
    ai = fmaf(gi, c, fmaf(-gr, s, ai));
  }
}
// acc += (gr + i gi) * e^{+2 pi i T/128}
template<int T>
__device__ __forceinline__ void caccP_t(float gr, float gi, float& ar, float& ai) {
  constexpr int t = T & 127;
  if constexpr (t == 0)       { ar += gr; ai += gi; }
  else if constexpr (t == 64) { ar -= gr; ai -= gi; }
  else if constexpr (t == 32) { ar -= gi; ai += gr; }
  else if constexpr (t == 96) { ar += gi; ai -= gr; }
  else {
    constexpr float c = twcos(t), s = twsin(t);
    ar = fmaf(gr, c, fmaf(-gi, s, ar));
    ai = fmaf(gi, c, fmaf(gr, s, ai));
  }
}
// (ar,ai) *= e^{-2 pi i T/128}
template<int T>
__device__ __forceinline__ void crotN_t(float& ar, float& ai) {
  constexpr int t = T & 127;
  if constexpr (t == 0) {}
  else if constexpr (t == 64) { ar = -ar; ai = -ai; }
  else if constexpr (t == 32) { const float r = ar; ar = ai; ai = -r; }
  else if constexpr (t == 96) { const float r = ar; ar = -ai; ai = r; }
  else {
    constexpr float c = twcos(t), s = twsin(t);
    const float r = ar;
    ar = fmaf(r, c, ai * s);
    ai = fmaf(ai, c, -r * s);
  }
}
// (ar,ai) *= e^{+2 pi i T/128}
template<int T>
__device__ __forceinline__ void crotP_t(float& ar, float& ai) {
  constexpr int t = T & 127;
  if constexpr (t == 0) {}
  else if constexpr (t == 64) { ar = -ar; ai = -ai; }
  else if constexpr (t == 32) { const float r = ar; ar = -ai; ai = r; }
  else if constexpr (t == 96) { const float r = ar; ar = ai;  ai = -r; }
  else {
    constexpr float c = twcos(t), s = twsin(t);
    const float r = ar;
    ar = fmaf(r, c, -(ai * s));
    ai = fmaf(ai, c, r * s);
  }
}

// ------------------------------------------------- weight transpose: (i,o,kx,ky) -> [kk][i][o]
__global__ __launch_bounds__(256) void k_wt(const float* __restrict__ wre,
                                            const float* __restrict__ wim,
                                            float* __restrict__ wtr,
                                            float* __restrict__ wti) {
  __shared__ float buf[64 * 257];
  const int i = blockIdx.x & 63;
  const float* src = (blockIdx.x < 64) ? wre : wim;
  float* dst       = (blockIdx.x < 64) ? wtr : wti;
  const float* s = src + (size_t)i * 16384;
  for (int t = threadIdx.x; t < 16384; t += 256) {
    int o = t >> 8, kk = t & 255;
    buf[o * 257 + kk] = s[t];
  }
  __syncthreads();
  for (int t = threadIdx.x; t < 16384; t += 256) {
    int kk = t >> 6, o = t & 63;
    dst[(size_t)kk * 4096 + i * 64 + o] = buf[o * 257 + kk];
  }
}

// ---------------------------------------------------------------- K1 helpers
template<int K>
__device__ __forceinline__ void k1_init(float (&Tr)[16], float (&Ti)[16],
                                        float (&Rr)[16], float (&Ri)[16]) {
  if constexpr (K < 16) {
    Tr[K] = 0.f; Ti[K] = 0.f; Rr[K] = 1.f; Ri[K] = 0.f;
    k1_init<K + 1>(Tr, Ti, Rr, Ri);
  }
}
template<int W1>
__device__ __forceinline__ void k1_ld8(const float* xp, int w0, float (&v)[8]) {
  if constexpr (W1 < 8) {
    v[W1] = xp[(W1 * 16 + w0) * NC];
    k1_ld8<W1 + 1>(xp, w0, v);
  }
}
template<int W1>
__device__ __forceinline__ void k1_cp8(float (&a)[8], const float (&b)[8]) {
  if constexpr (W1 < 8) { a[W1] = b[W1]; k1_cp8<W1 + 1>(a, b); }
}
// accumulate T[KY] += G_{KY&7} * R[KY], then R[KY] *= e^{-2 pi i KY/128}
template<int KY>
__device__ __forceinline__ void k1_acc(float g0r, float g4r, float g1r, float g1i,
                                       float g2r, float g2i, float g3r, float g3i,
                                       float (&Tr)[16], float (&Ti)[16],
                                       float (&Rr)[16], float (&Ri)[16]) {
  if constexpr (KY < 16) {
    constexpr int p = KY & 7;
    if constexpr (p == 0 || p == 4) {
      const float gr = (p == 0) ? g0r : g4r;
      Tr[KY] = fmaf(gr, Rr[KY], Tr[KY]);
      Ti[KY] = fmaf(gr, Ri[KY], Ti[KY]);
    } else {
      float gr, gi;
      if constexpr (p == 1)      { gr = g1r; gi = g1i; }
      else if constexpr (p == 2) { gr = g2r; gi = g2i; }
      else if constexpr (p == 3) { gr = g3r; gi = g3i; }
      else if constexpr (p == 5) { gr = g3r; gi = -g3i; }
      else if constexpr (p == 6) { gr = g2r; gi = -g2i; }
      else                       { gr = g1r; gi = -g1i; }
      Tr[KY] = fmaf(gr, Rr[KY], fmaf(-gi, Ri[KY], Tr[KY]));
      Ti[KY] = fmaf(gr, Ri[KY], fmaf( gi, Rr[KY], Ti[KY]));
    }
    crotN_t<KY>(Rr[KY], Ri[KY]);
    k1_acc<KY + 1>(g0r, g4r, g1r, g1i, g2r, g2i, g3r, g3i, Tr, Ti, Rr, Ri);
  }
}
template<int KY>
__device__ __forceinline__ void k1_store(float* t1r, float* t1i,
                                         const float (&Tr)[16], const float (&Ti)[16]) {
  if constexpr (KY < 16) {
    t1r[(size_t)KY * (NH * NC)] = Tr[KY];
    t1i[(size_t)KY * (NH * NC)] = Ti[KY];
    k1_store<KY + 1>(t1r, t1i, Tr, Ti);
  }
}

// K1: T1[b][ky][h][i] = sum_w x[b,h,w,i] e^{-2pi i ky w/128}
__global__ __launch_bounds__(256, 2) void k1_wdft(const float* __restrict__ x,
                                                  float* __restrict__ t1r,
                                                  float* __restrict__ t1i) {
  const int wid  = threadIdx.x >> 6;
  const int lane = threadIdx.x & 63;            // i
  const int slab = blockIdx.x * 4 + wid;        // b*128 + h
  const float* xp = x + (size_t)slab * (NW * NC) + lane;
  float Tr[16], Ti[16], Rr[16], Ri[16];
  k1_init<0>(Tr, Ti, Rr, Ri);
  float xv[8], nx[8];
  k1_ld8<0>(xp, 0, xv);
  for (int w0 = 0; w0 < 16; ++w0) {
    if (w0 < 15) k1_ld8<0>(xp, w0 + 1, nx);
    // 8-point real DFT over w1 (exact-constant butterflies)
    const float s0 = xv[0] + xv[4], d0 = xv[0] - xv[4];
    const float s1 = xv[1] + xv[5], d1 = xv[1] - xv[5];
    const float s2 = xv[2] + xv[6], d2 = xv[2] - xv[6];
    const float s3 = xv[3] + xv[7], d3 = xv[3] - xv[7];
    const float e0 = s0 + s2, e1 = s0 - s2;
    const float f0 = s1 + s3, f1 = s1 - s3;
    const float u = R2F * (d1 - d3), v = R2F * (d1 + d3);
    const float g0r = e0 + f0;
    const float g4r = e0 - f0;
    const float g1r = d0 + u, g1i = -(d2 + v);
    const float g2r = e1,     g2i = -f1;
    const float g3r = d0 - u, g3i = d2 - v;
    k1_acc<0>(g0r, g4r, g1r, g1i, g2r, g2i, g3r, g3i, Tr, Ti, Rr, Ri);
    k1_cp8<0>(xv, nx);
  }
  const int b = slab >> 7, h = slab & 127;
  const size_t base = ((size_t)b * 2048 + h) * NC + lane;   // ((b*16+0)*128+h)*64+i
  k1_store<0>(t1r + base, t1i + base, Tr, Ti);
}

// ---------------------------------------------------------------- K2a helpers
template<int K>
__device__ __forceinline__ void k2a_zero(float (&Ar)[16], float (&Ai)[16]) {
  if constexpr (K < 16) { Ar[K] = 0.f; Ai[K] = 0.f; k2a_zero<K + 1>(Ar, Ai); }
}
template<int KX, int J>
__device__ __forceinline__ void k2a_kx(float re, float im, float (&Ar)[16], float (&Ai)[16]) {
  if constexpr (KX < 16) {
    caccN_t<(KX * J) & 127>(re, im, Ar[KX], Ai[KX]);
    k2a_kx<KX + 1, J>(re, im, Ar, Ai);
  }
}
template<int J>
__device__ __forceinline__ void k2a_j(const float* pr, const float* pi,
                                      float (&Ar)[16], float (&Ai)[16]) {
  if constexpr (J < 8) {
    const float re = pr[J * NC];
    const float im = pi[J * NC];
    k2a_kx<0, J>(re, im, Ar, Ai);
    k2a_j<J + 1>(pr, pi, Ar, Ai);
  }
}
template<int G, int KX>
__device__ __forceinline__ void k2a_rotg(float (&Ar)[16], float (&Ai)[16]) {
  if constexpr (KX < 16) {
    crotN_t<(8 * KX * G) & 127>(Ar[KX], Ai[KX]);
    k2a_rotg<G, KX + 1>(Ar, Ai);
  }
}
template<int KX>
__device__ __forceinline__ void k2a_ldsw(float* pr, float* pi,
                                         const float (&Ar)[16], const float (&Ai)[16]) {
  if constexpr (KX < 16) {
    pr[KX * 64] = Ar[KX]; pi[KX * 64] = Ai[KX];
    k2a_ldsw<KX + 1>(pr, pi, Ar, Ai);
  }
}
template<int KX>
__device__ __forceinline__ void k2a_ldsa(float* pr, float* pi,
                                         const float (&Ar)[16], const float (&Ai)[16]) {
  if constexpr (KX < 16) {
    pr[KX * 64] += Ar[KX]; pi[KX * 64] += Ai[KX];
    k2a_ldsa<KX + 1>(pr, pi, Ar, Ai);
  }
}

// K2a: X[kx*16+ky][b][i] = sum_h T1[b][ky][h][i] e^{-2pi i kx h/128}
// 1024 threads: wave q (16 waves) owns h in [8q, 8q+8); lane = i.
__global__ __launch_bounds__(1024, 4) void k2a_hdft(const float* __restrict__ t1r,
                                                    const float* __restrict__ t1i,
                                                    float* __restrict__ xre,
                                                    float* __restrict__ xim) {
  __shared__ float lpr[8][16][64];
  __shared__ float lpi[8][16][64];
  const int bk   = blockIdx.x;                  // b*16 + ky
  const int q    = threadIdx.x >> 6;
  const int lane = threadIdx.x & 63;            // i
  const float* pr = t1r + (size_t)bk * (NH * NC) + (q * 8) * NC + lane;
  const float* pi = t1i + (size_t)bk * (NH * NC) + (q * 8) * NC + lane;
  float Ar[16], Ai[16];
  k2a_zero<0>(Ar, Ai);
  k2a_j<0>(pr, pi, Ar, Ai);
  // post-rotate by e^{-2 pi i kx * 8q / 128} (wave-uniform switch, all-literal)
  switch (q) {
    case 1:  k2a_rotg<1, 0>(Ar, Ai);  break;
    case 2:  k2a_rotg<2, 0>(Ar, Ai);  break;
    case 3:  k2a_rotg<3, 0>(Ar, Ai);  break;
    case 4:  k2a_rotg<4, 0>(Ar, Ai);  break;
    case 5:  k2a_rotg<5, 0>(Ar, Ai);  break;
    case 6:  k2a_rotg<6, 0>(Ar, Ai);  break;
    case 7:  k2a_rotg<7, 0>(Ar, Ai);  break;
    case 8:  k2a_rotg<8, 0>(Ar, Ai);  break;
    case 9:  k2a_rotg<9, 0>(Ar, Ai);  break;
    case 10: k2a_rotg<10, 0>(Ar, Ai); break;
    case 11: k2a_rotg<11, 0>(Ar, Ai); break;
    case 12: k2a_rotg<12, 0>(Ar, Ai); break;
    case 13: k2a_rotg<13, 0>(Ar, Ai); break;
    case 14: k2a_rotg<14, 0>(Ar, Ai); break;
    case 15: k2a_rotg<15, 0>(Ar, Ai); break;
    default: break;
  }
  float* wpr = &lpr[q & 7][0][lane];
  float* wpi = &lpi[q & 7][0][lane];
  if (q < 8) k2a_ldsw<0>(wpr, wpi, Ar, Ai);
  __syncthreads();
  if (q >= 8) k2a_ldsa<0>(wpr, wpi, Ar, Ai);
  __syncthreads();
  // final reduce: 1024 threads = (kx, i)
  const int kx = threadIdx.x >> 6;
  const int i  = threadIdx.x & 63;
  float sr = 0.f, si = 0.f;
#pragma unroll
  for (int p = 0; p < 8; ++p) { sr += lpr[p][kx][i]; si += lpi[p][kx][i]; }
  const int b = bk >> 4, ky = bk & 15;
  const size_t idx = (size_t)(kx * NM + ky) * (NB * NC) + b * NC + i;
  xre[idx] = sr;
  xim[idx] = si;
}

// ---------------------------------------------------------------- K2b: channel mix per mode
__global__ __launch_bounds__(256, 2) void k2b_mix(const float* __restrict__ xre,
                                                  const float* __restrict__ xim,
                                                  const float* __restrict__ wtr,
                                                  const float* __restrict__ wti,
                                                  float* __restrict__ ore,
                                                  float* __restrict__ oim) {
  __shared__ __align__(16) float lwr[4096], lwi[4096];  // [i][o]
  __shared__ __align__(16) float lxr[1024], lxi[1024];  // [b][i]
  const int kk = blockIdx.x;
  for (int t = threadIdx.x; t < 4096; t += 256) {
    lwr[t] = wtr[(size_t)kk * 4096 + t];
    lwi[t] = wti[(size_t)kk * 4096 + t];
  }
  for (int t = threadIdx.x; t < 1024; t += 256) {
    lxr[t] = xre[(size_t)kk * 1024 + t];
    lxi[t] = xim[(size_t)kk * 1024 + t];
  }
  __syncthreads();
  const int o  = threadIdx.x & 63;
  const int bq = threadIdx.x >> 6;
  float accr[4] = {0, 0, 0, 0}, acci[4] = {0, 0, 0, 0};
  for (int iq = 0; iq < 16; ++iq) {
    float xrv[4][4], xiv[4][4];
#pragma unroll
    for (int p = 0; p < 4; ++p) {
      const int b = bq * 4 + p;
      float4 vr = ((const float4*)lxr)[b * 16 + iq];
      float4 vi = ((const float4*)lxi)[b * 16 + iq];
      xrv[p][0] = vr.x; xrv[p][1] = vr.y; xrv[p][2] = vr.z; xrv[p][3] = vr.w;
      xiv[p][0] = vi.x; xiv[p][1] = vi.y; xiv[p][2] = vi.z; xiv[p][3] = vi.w;
    }
#pragma unroll
    for (int j = 0; j < 4; ++j) {
      const int i2 = iq * 4 + j;
      const float wr = lwr[i2 * 64 + o];
      const float wi = lwi[i2 * 64 + o];
#pragma unroll
      for (int p = 0; p < 4; ++p) {
        accr[p] = fmaf(xrv[p][j], wr, fmaf(-xiv[p][j], wi, accr[p]));
        acci[p] = fmaf(xrv[p][j], wi, fmaf(xiv[p][j], wr, acci[p]));
      }
    }
  }
#pragma unroll
  for (int p = 0; p < 4; ++p) {
    const int b = bq * 4 + p;
    ore[(size_t)kk * 1024 + b * 64 + o] = accr[p];
    oim[(size_t)kk * 1024 + b * 64 + o] = acci[p];
  }
}

// ---------------------------------------------------------------- K3: h-inverse -> T2[b][h][ky][o]
// T2[b][h][ky][o] = cfac(ky)/16384 * sum_kx O[kx*16+ky][b][o] e^{+2pi i kx h/128}
__global__ __launch_bounds__(256, 2) void k3_hidft(const float* __restrict__ ore,
                                                   const float* __restrict__ oim,
                                                   float* __restrict__ t2r,
                                                   float* __restrict__ t2i) {
  const int b = blockIdx.x >> 5, hq = blockIdx.x & 31;
  const int q = threadIdx.x >> 6, lane = threadIdx.x & 63;   // lane = o
  const int ky0 = q * 4;
  // per-j step twiddle e^{+2 pi i (4hq+j)/128}, built from literal bit rotations
  float sc[4], ss[4];
  {
    const int h0 = 4 * hq;
    float wr = 1.f, wi = 0.f;
    if (h0 & 4)  crotP_t<4>(wr, wi);
    if (h0 & 8)  crotP_t<8>(wr, wi);
    if (h0 & 16) crotP_t<16>(wr, wi);
    if (h0 & 32) crotP_t<32>(wr, wi);
    if (h0 & 64) crotP_t<64>(wr, wi);
    sc[0] = wr; ss[0] = wi;
    crotP_t<1>(wr, wi); sc[1] = wr; ss[1] = wi;
    crotP_t<1>(wr, wi); sc[2] = wr; ss[2] = wi;
    crotP_t<1>(wr, wi); sc[3] = wr; ss[3] = wi;
  }
  float Rr[4] = {1.f, 1.f, 1.f, 1.f}, Ri[4] = {0.f, 0.f, 0.f, 0.f};
  float tr[4][4], ti[4][4];
#pragma unroll
  for (int j = 0; j < 4; ++j)
#pragma unroll
    for (int k = 0; k < 4; ++k) { tr[j][k] = 0.f; ti[j][k] = 0.f; }
  const size_t obase = (size_t)b * NO + lane;
  for (int kx = 0; kx < 16; ++kx) {
    float orv[4], oiv[4];
#pragma unroll
    for (int k = 0; k < 4; ++k) {
      const size_t idx = (size_t)(kx * 16 + ky0 + k) * (NB * NO) + obase;
      orv[k] = ore[idx];
      oiv[k] = oim[idx];
    }
#pragma unroll
    for (int j = 0; j < 4; ++j)
#pragma unroll
      for (int k = 0; k < 4; ++k) {
        tr[j][k] = fmaf(orv[k], Rr[j], fmaf(-oiv[k], Ri[j], tr[j][k]));
        ti[j][k] = fmaf(orv[k], Ri[j], fmaf( oiv[k], Rr[j], ti[j][k]));
      }
#pragma unroll
    for (int j = 0; j < 4; ++j) {
      const float nr = fmaf(Rr[j], sc[j], -(Ri[j] * ss[j]));
      const float ni = fmaf(Rr[j], ss[j], Ri[j] * sc[j]);
      Rr[j] = nr; Ri[j] = ni;
    }
  }
#pragma unroll
  for (int j = 0; j < 4; ++j) {
    const int h = hq * 4 + j;
#pragma unroll
    for (int k = 0; k < 4; ++k) {
      const int ky = ky0 + k;
      const float scale = (ky == 0 ? 1.0f : 2.0f) * (1.0f / 16384.0f);
      const size_t idx = ((size_t)(b * NH + h) * NM + ky) * NO + lane;
      t2r[idx] = tr[j][k] * scale;
      t2i[idx] = ti[j][k] * scale;
    }
  }
}

// ---------------------------------------------------------------- K5 helpers
template<int KY>
__device__ __forceinline__ void k5_load(const float* pr, const float* pi,
                                        float (&Tr)[16], float (&Ti)[16]) {
  if constexpr (KY < 16) {
    Tr[KY] = pr[KY * NO];
    Ti[KY] = pi[KY * NO];
    k5_load<KY + 1>(pr, pi, Tr, Ti);
  }
}
template<int KY, int W0>
__device__ __forceinline__ void k5_u(const float (&Tr)[16], const float (&Ti)[16],
                                     float (&Ur)[8], float (&Ui)[8]) {
  if constexpr (KY < 16) {
    caccP_t<(KY * W0) & 127>(Tr[KY], Ti[KY], Ur[KY & 7], Ui[KY & 7]);
    k5_u<KY + 1, W0>(Tr, Ti, Ur, Ui);
  }
}
template<int P>
__device__ __forceinline__ void k5_uzero(float (&Ur)[8], float (&Ui)[8]) {
  if constexpr (P < 8) { Ur[P] = 0.f; Ui[P] = 0.f; k5_uzero<P + 1>(Ur, Ui); }
}
template<int W0>
__device__ __forceinline__ void k5_w0(const float (&Tr)[16], const float (&Ti)[16],
                                      float* yp) {
  if constexpr (W0 < 16) {
    float Ur[8], Ui[8];
    k5_uzero<0>(Ur, Ui);
    k5_u<0, W0>(Tr, Ti, Ur, Ui);
    // 8-pt real-part inverse butterfly (verified round 2)
    const float A  = Ur[0], B = Ur[4];
    const float Cr = Ur[2] + Ur[6], Ci = Ui[2] - Ui[6];
    const float Dr = Ur[1] + Ur[7], Di = Ui[1] - Ui[7];
    const float Er = Ur[3] + Ur[5], Ei = Ui[3] - Ui[5];
    const float P = A + B, M = A - B;
    const float DE = Dr + Er, IE = Di - Ei;
    const float X1 = R2F * ((Dr - Di) - (Er + Ei));
    const float X3 = R2F * ((Dr + Di) - (Er - Ei));
    const float MmC = M - Ci, MpC = M + Ci, PpC = P + Cr, PmC = P - Cr;
    yp[(0 * 16 + W0) * NO] = PpC + DE;
    yp[(4 * 16 + W0) * NO] = PpC - DE;
    yp[(2 * 16 + W0) * NO] = PmC - IE;
    yp[(6 * 16 + W0) * NO] = PmC + IE;
    yp[(1 * 16 + W0) * NO] = MmC + X1;
    yp[(5 * 16 + W0) * NO] = MmC - X1;
    yp[(3 * 16 + W0) * NO] = MpC - X3;
    yp[(7 * 16 + W0) * NO] = MpC + X3;
    k5_w0<W0 + 1>(Tr, Ti, yp);
  }
}

// K5: y[b,h,w,o] = Re sum_ky T2[b][h][ky][o] e^{+2pi i ky w/128}
__global__ __launch_bounds__(256, 2) void k5_widft(const float* __restrict__ t2r,
                                                   const float* __restrict__ t2i,
                                                   float* __restrict__ y) {
  const int wid  = threadIdx.x >> 6;
  const int lane = threadIdx.x & 63;            // o
  const int slab = blockIdx.x * 4 + wid;        // b*128 + h
  const float* pr = t2r + (size_t)slab * (NM * NO) + lane;
  const float* pi = t2i + (size_t)slab * (NM * NO) + lane;
  float Tr[16], Ti[16];
  k5_load<0>(pr, pi, Tr, Ti);
  float* yp = y + (size_t)slab * (NW * NO) + lane;
  k5_w0<0>(Tr, Ti, yp);
}

extern "C" void kernel_launch(void* const* d_in, const int* in_sizes, int n_in,
                              void* d_out, int out_size, void* d_ws, size_t ws_size,
                              hipStream_t stream) {
  const float* x   = (const float*)d_in[0];
  const float* wre = (const float*)d_in[1];
  const float* wim = (const float*)d_in[2];
  float* ws  = (float*)d_ws;
  float* wtr = ws + OFF_WTR;
  float* wti = ws + OFF_WTI;
  float* ar  = ws + OFF_AR;   // T1, later T2 (re)
  float* ai  = ws + OFF_AI;   // T1, later T2 (im)
  float* xr  = ws + OFF_XR;
  float* xi  = ws + OFF_XI;
  float* orr = ws + OFF_OR;
  float* oii = ws + OFF_OI;
  float* y   = (float*)d_out;

  k_wt<<<128, 256, 0, stream>>>(wre, wim, wtr, wti);
  k1_wdft<<<512, 256, 0, stream>>>(x, ar, ai);
  k2a_hdft<<<NB * NM, 1024, 0, stream>>>(ar, ai, xr, xi);
  k2b_mix<<<NM * NM, 256, 0, stream>>>(xr, xi, wtr, wti, orr, oii);
  k3_hidft<<<512, 256, 0, stream>>>(orr, oii, ar, ai);   // ar/ai now hold T2[b][h][ky][o]
  k5_widft<<<512, 256, 0, stream>>>(ar, ai, y);
}

// Round 5
// 155.612 us; speedup vs baseline: 3.6817x; 1.0852x over previous
//
#include <hip/hip_runtime.h>

#define NB 16
#define NH 128
#define NW 128
#define NC 64   // in channels
#define NO 64   // out channels
#define NM 16   // modes

// workspace float offsets
#define OFF_WTR  0                          // 1048576: Wt_re[kk][i][o]
#define OFF_WTI  (OFF_WTR + 1048576)
#define OFF_AR   (OFF_WTI + 1048576)        // 2097152: T1_re[b][ky][h][i] / T2_re[b][h][ky][o]
#define OFF_AI   (OFF_AR + 2097152)
#define OFF_XR   (OFF_AI + 2097152)         // 262144: X_re[kk][b][i]
#define OFF_XI   (OFF_XR + 262144)
#define OFF_OR   (OFF_XI + 262144)          // 262144: O_re[kk][b][o]
#define OFF_OI   (OFF_OR + 262144)

#define R2F 0.70710678118654752f

// cos(pi*t/64) for t=0..32
constexpr float CQ[33] = {
  1.000000000f, 0.998795456f, 0.995184727f, 0.989176510f,
  0.980785280f, 0.970031253f, 0.956940336f, 0.941544065f,
  0.923879533f, 0.903989293f, 0.881921264f, 0.857728610f,
  0.831469612f, 0.803207531f, 0.773010453f, 0.740951125f,
  0.707106781f, 0.671558955f, 0.634393284f, 0.595699304f,
  0.555570233f, 0.514102744f, 0.471396737f, 0.427555093f,
  0.382683432f, 0.336889853f, 0.290284677f, 0.242980180f,
  0.195090322f, 0.146730474f, 0.098017140f, 0.049067674f,
  0.000000000f };

__host__ __device__ constexpr float twcos(int t) {   // cos(2*pi*t/128)
  t &= 127;
  return (t <= 32) ? CQ[t] : (t < 64) ? -CQ[64 - t] : (t <= 96) ? -CQ[t - 64] : CQ[128 - t];
}
__host__ __device__ constexpr float twsin(int t) { return twcos(t + 96); }

// ---- template twiddle ops (compile-time exponent; folding guaranteed) ----
template<int T>
__device__ __forceinline__ void caccN_t(float gr, float gi, float& ar, float& ai) {
  constexpr int t = T & 127;
  if constexpr (t == 0)       { ar += gr; ai += gi; }
  else if constexpr (t == 64) { ar -= gr; ai -= gi; }
  else if constexpr (t == 32) { ar += gi; ai -= gr; }
  else if constexpr (t == 96) { ar -= gi; ai += gr; }
  else {
    constexpr float c = twcos(t), s = twsin(t);
    ar = fmaf(gr, c, fmaf(gi, s, ar));
    ai = fmaf(gi, c, fmaf(-gr, s, ai));
  }
}
template<int T>
__device__ __forceinline__ void caccP_t(float gr, float gi, float& ar, float& ai) {
  constexpr int t = T & 127;
  if constexpr (t == 0)       { ar += gr; ai += gi; }
  else if constexpr (t == 64) { ar -= gr; ai -= gi; }
  else if constexpr (t == 32) { ar -= gi; ai += gr; }
  else if constexpr (t == 96) { ar += gi; ai -= gr; }
  else {
    constexpr float c = twcos(t), s = twsin(t);
    ar = fmaf(gr, c, fmaf(-gi, s, ar));
    ai = fmaf(gi, c, fmaf(gr, s, ai));
  }
}
template<int T>
__device__ __forceinline__ void crotN_t(float& ar, float& ai) {
  constexpr int t = T & 127;
  if constexpr (t == 0) {}
  else if constexpr (t == 64) { ar = -ar; ai = -ai; }
  else if constexpr (t == 32) { const float r = ar; ar = ai; ai = -r; }
  else if constexpr (t == 96) { const float r = ar; ar = -ai; ai = r; }
  else {
    constexpr float c = twcos(t), s = twsin(t);
    const float r = ar;
    ar = fmaf(r, c, ai * s);
    ai = fmaf(ai, c, -r * s);
  }
}
template<int T>
__device__ __forceinline__ void crotP_t(float& ar, float& ai) {
  constexpr int t = T & 127;
  if constexpr (t == 0) {}
  else if constexpr (t == 64) { ar = -ar; ai = -ai; }
  else if constexpr (t == 32) { const float r = ar; ar = -ai; ai = r; }
  else if constexpr (t == 96) { const float r = ar; ar = ai;  ai = -r; }
  else {
    constexpr float c = twcos(t), s = twsin(t);
    const float r = ar;
    ar = fmaf(r, c, -(ai * s));
    ai = fmaf(ai, c, r * s);
  }
}

// ------------------------------------------------- weight transpose: (i,o,kx,ky) -> [kk][i][o]
__global__ __launch_bounds__(256) void k_wt(const float* __restrict__ wre,
                                            const float* __restrict__ wim,
                                            float* __restrict__ wtr,
                                            float* __restrict__ wti) {
  __shared__ float buf[64 * 257];
  const int i = blockIdx.x & 63;
  const float* src = (blockIdx.x < 64) ? wre : wim;
  float* dst       = (blockIdx.x < 64) ? wtr : wti;
  const float* s = src + (size_t)i * 16384;
  for (int t = threadIdx.x; t < 16384; t += 256) {
    int o = t >> 8, kk = t & 255;
    buf[o * 257 + kk] = s[t];
  }
  __syncthreads();
  for (int t = threadIdx.x; t < 16384; t += 256) {
    int kk = t >> 6, o = t & 63;
    dst[(size_t)kk * 4096 + i * 64 + o] = buf[o * 257 + kk];
  }
}

// ---------------------------------------------------------------- K1 helpers
template<int K>
__device__ __forceinline__ void k1_zeroT(float (&Tr)[16], float (&Ti)[16]) {
  if constexpr (K < 16) { Tr[K] = 0.f; Ti[K] = 0.f; k1_zeroT<K + 1>(Tr, Ti); }
}
// R[K] = e^{-2 pi i K*P0/128}
template<int K, int P0>
__device__ __forceinline__ void k1_initR(float (&Rr)[16], float (&Ri)[16]) {
  if constexpr (K < 16) {
    constexpr int t = (K * P0) & 127;
    Rr[K] = twcos(t);
    Ri[K] = -twsin(t);
    k1_initR<K + 1, P0>(Rr, Ri);
  }
}
template<int W1>
__device__ __forceinline__ void k1_ld8(const float* xp, int w0, float (&v)[8]) {
  if constexpr (W1 < 8) {
    v[W1] = xp[(W1 * 16 + w0) * NC];
    k1_ld8<W1 + 1>(xp, w0, v);
  }
}
template<int W1>
__device__ __forceinline__ void k1_cp8(float (&a)[8], const float (&b)[8]) {
  if constexpr (W1 < 8) { a[W1] = b[W1]; k1_cp8<W1 + 1>(a, b); }
}
template<int KY>
__device__ __forceinline__ void k1_acc(float g0r, float g4r, float g1r, float g1i,
                                       float g2r, float g2i, float g3r, float g3i,
                                       float (&Tr)[16], float (&Ti)[16],
                                       float (&Rr)[16], float (&Ri)[16]) {
  if constexpr (KY < 16) {
    constexpr int p = KY & 7;
    if constexpr (p == 0 || p == 4) {
      const float gr = (p == 0) ? g0r : g4r;
      Tr[KY] = fmaf(gr, Rr[KY], Tr[KY]);
      Ti[KY] = fmaf(gr, Ri[KY], Ti[KY]);
    } else {
      float gr, gi;
      if constexpr (p == 1)      { gr = g1r; gi = g1i; }
      else if constexpr (p == 2) { gr = g2r; gi = g2i; }
      else if constexpr (p == 3) { gr = g3r; gi = g3i; }
      else if constexpr (p == 5) { gr = g3r; gi = -g3i; }
      else if constexpr (p == 6) { gr = g2r; gi = -g2i; }
      else                       { gr = g1r; gi = -g1i; }
      Tr[KY] = fmaf(gr, Rr[KY], fmaf(-gi, Ri[KY], Tr[KY]));
      Ti[KY] = fmaf(gr, Ri[KY], fmaf( gi, Rr[KY], Ti[KY]));
    }
    crotN_t<KY>(Rr[KY], Ri[KY]);
    k1_acc<KY + 1>(g0r, g4r, g1r, g1i, g2r, g2i, g3r, g3i, Tr, Ti, Rr, Ri);
  }
}
template<int K>
__device__ __forceinline__ void k1_ldswr(float* p, const float (&Tr)[16], const float (&Ti)[16]) {
  if constexpr (K < 16) {
    p[K * 64]        = Tr[K];
    p[(16 + K) * 64] = Ti[K];
    k1_ldswr<K + 1>(p, Tr, Ti);
  }
}
template<int K>
__device__ __forceinline__ void k1_ldsadd(const float* p, float (&Tr)[16], float (&Ti)[16]) {
  if constexpr (K < 16) {
    Tr[K] += p[K * 64];
    Ti[K] += p[(16 + K) * 64];
    k1_ldsadd<K + 1>(p, Tr, Ti);
  }
}
template<int KY>
__device__ __forceinline__ void k1_store(float* t1r, float* t1i,
                                         const float (&Tr)[16], const float (&Ti)[16]) {
  if constexpr (KY < 16) {
    t1r[(size_t)KY * (NH * NC)] = Tr[KY];
    t1i[(size_t)KY * (NH * NC)] = Ti[KY];
    k1_store<KY + 1>(t1r, t1i, Tr, Ti);
  }
}

// K1: T1[b][ky][h][i] = sum_w x[b,h,w,i] e^{-2pi i ky w/128}
// 4 waves/block: (slab-in-block sq, w0-half). Grid 1024 -> 4 waves/SIMD.
__global__ __launch_bounds__(256, 4) void k1_wdft(const float* __restrict__ x,
                                                  float* __restrict__ t1r,
                                                  float* __restrict__ t1i) {
  __shared__ float lds[2][32][64];
  const int wv   = threadIdx.x >> 6;
  const int lane = threadIdx.x & 63;            // i
  const int sq   = wv >> 1;
  const int half = wv & 1;
  const int slab = blockIdx.x * 2 + sq;         // b*128 + h
  const float* xp = x + (size_t)slab * (NW * NC) + lane;
  float Tr[16], Ti[16], Rr[16], Ri[16];
  k1_zeroT<0>(Tr, Ti);
  if (half == 0) k1_initR<0, 0>(Rr, Ri);
  else           k1_initR<0, 8>(Rr, Ri);
  float xv[8], nx[8];
  k1_ld8<0>(xp, half * 8, xv);
  for (int it = 0; it < 8; ++it) {
    const int w0 = half * 8 + it;
    if (it < 7) k1_ld8<0>(xp, w0 + 1, nx);
    // 8-point real DFT over w1 (exact-constant butterflies)
    const float s0 = xv[0] + xv[4], d0 = xv[0] - xv[4];
    const float s1 = xv[1] + xv[5], d1 = xv[1] - xv[5];
    const float s2 = xv[2] + xv[6], d2 = xv[2] - xv[6];
    const float s3 = xv[3] + xv[7], d3 = xv[3] - xv[7];
    const float e0 = s0 + s2, e1 = s0 - s2;
    const float f0 = s1 + s3, f1 = s1 - s3;
    const float u = R2F * (d1 - d3), v = R2F * (d1 + d3);
    const float g0r = e0 + f0;
    const float g4r = e0 - f0;
    const float g1r = d0 + u, g1i = -(d2 + v);
    const float g2r = e1,     g2i = -f1;
    const float g3r = d0 - u, g3i = d2 - v;
    k1_acc<0>(g0r, g4r, g1r, g1i, g2r, g2i, g3r, g3i, Tr, Ti, Rr, Ri);
    k1_cp8<0>(xv, nx);
  }
  float* lp = &lds[sq][0][lane];
  if (half) k1_ldswr<0>(lp, Tr, Ti);
  __syncthreads();
  if (!half) {
    k1_ldsadd<0>(lp, Tr, Ti);
    const int b = slab >> 7, h = slab & 127;
    const size_t base = ((size_t)b * 2048 + h) * NC + lane;
    k1_store<0>(t1r + base, t1i + base, Tr, Ti);
  }
}

// ---------------------------------------------------------------- K2a helpers
template<int K>
__device__ __forceinline__ void k2a_zero(float (&Ar)[16], float (&Ai)[16]) {
  if constexpr (K < 16) { Ar[K] = 0.f; Ai[K] = 0.f; k2a_zero<K + 1>(Ar, Ai); }
}
template<int KX, int J>
__device__ __forceinline__ void k2a_kx(float re, float im, float (&Ar)[16], float (&Ai)[16]) {
  if constexpr (KX < 16) {
    caccN_t<(KX * J) & 127>(re, im, Ar[KX], Ai[KX]);
    k2a_kx<KX + 1, J>(re, im, Ar, Ai);
  }
}
template<int J>
__device__ __forceinline__ void k2a_j(const float* pr, const float* pi,
                                      float (&Ar)[16], float (&Ai)[16]) {
  if constexpr (J < 8) {
    const float re = pr[J * NC];
    const float im = pi[J * NC];
    k2a_kx<0, J>(re, im, Ar, Ai);
    k2a_j<J + 1>(pr, pi, Ar, Ai);
  }
}
template<int G, int KX>
__device__ __forceinline__ void k2a_rotg(float (&Ar)[16], float (&Ai)[16]) {
  if constexpr (KX < 16) {
    crotN_t<(8 * KX * G) & 127>(Ar[KX], Ai[KX]);
    k2a_rotg<G, KX + 1>(Ar, Ai);
  }
}
template<int KX>
__device__ __forceinline__ void k2a_ldsw(float* pr, float* pi,
                                         const float (&Ar)[16], const float (&Ai)[16]) {
  if constexpr (KX < 16) {
    pr[KX * 64] = Ar[KX]; pi[KX * 64] = Ai[KX];
    k2a_ldsw<KX + 1>(pr, pi, Ar, Ai);
  }
}
template<int KX>
__device__ __forceinline__ void k2a_ldsa(float* pr, float* pi,
                                         const float (&Ar)[16], const float (&Ai)[16]) {
  if constexpr (KX < 16) {
    pr[KX * 64] += Ar[KX]; pi[KX * 64] += Ai[KX];
    k2a_ldsa<KX + 1>(pr, pi, Ar, Ai);
  }
}

// K2a: X[kx*16+ky][b][i] = sum_h T1[b][ky][h][i] e^{-2pi i kx h/128}
__global__ __launch_bounds__(1024, 4) void k2a_hdft(const float* __restrict__ t1r,
                                                    const float* __restrict__ t1i,
                                                    float* __restrict__ xre,
                                                    float* __restrict__ xim) {
  __shared__ float lpr[8][16][64];
  __shared__ float lpi[8][16][64];
  const int bk   = blockIdx.x;                  // b*16 + ky
  const int q    = threadIdx.x >> 6;
  const int lane = threadIdx.x & 63;            // i
  const float* pr = t1r + (size_t)bk * (NH * NC) + (q * 8) * NC + lane;
  const float* pi = t1i + (size_t)bk * (NH * NC) + (q * 8) * NC + lane;
  float Ar[16], Ai[16];
  k2a_zero<0>(Ar, Ai);
  k2a_j<0>(pr, pi, Ar, Ai);
  switch (q) {   // post-rotate by e^{-2 pi i kx * 8q / 128}
    case 1:  k2a_rotg<1, 0>(Ar, Ai);  break;
    case 2:  k2a_rotg<2, 0>(Ar, Ai);  break;
    case 3:  k2a_rotg<3, 0>(Ar, Ai);  break;
    case 4:  k2a_rotg<4, 0>(Ar, Ai);  break;
    case 5:  k2a_rotg<5, 0>(Ar, Ai);  break;
    case 6:  k2a_rotg<6, 0>(Ar, Ai);  break;
    case 7:  k2a_rotg<7, 0>(Ar, Ai);  break;
    case 8:  k2a_rotg<8, 0>(Ar, Ai);  break;
    case 9:  k2a_rotg<9, 0>(Ar, Ai);  break;
    case 10: k2a_rotg<10, 0>(Ar, Ai); break;
    case 11: k2a_rotg<11, 0>(Ar, Ai); break;
    case 12: k2a_rotg<12, 0>(Ar, Ai); break;
    case 13: k2a_rotg<13, 0>(Ar, Ai); break;
    case 14: k2a_rotg<14, 0>(Ar, Ai); break;
    case 15: k2a_rotg<15, 0>(Ar, Ai); break;
    default: break;
  }
  float* wpr = &lpr[q & 7][0][lane];
  float* wpi = &lpi[q & 7][0][lane];
  if (q < 8) k2a_ldsw<0>(wpr, wpi, Ar, Ai);
  __syncthreads();
  if (q >= 8) k2a_ldsa<0>(wpr, wpi, Ar, Ai);
  __syncthreads();
  const int kx = threadIdx.x >> 6;
  const int i  = threadIdx.x & 63;
  float sr = 0.f, si = 0.f;
#pragma unroll
  for (int p = 0; p < 8; ++p) { sr += lpr[p][kx][i]; si += lpi[p][kx][i]; }
  const int b = bk >> 4, ky = bk & 15;
  const size_t idx = (size_t)(kx * NM + ky) * (NB * NC) + b * NC + i;
  xre[idx] = sr;
  xim[idx] = si;
}

// ---------------------------------------------------------------- K2b: channel mix per mode
// 512 threads: 8 waves, wave bq owns b in {2bq, 2bq+1}; lane = o.
__global__ __launch_bounds__(512, 2) void k2b_mix(const float* __restrict__ xre,
                                                  const float* __restrict__ xim,
                                                  const float* __restrict__ wtr,
                                                  const float* __restrict__ wti,
                                                  float* __restrict__ ore,
                                                  float* __restrict__ oim) {
  __shared__ __align__(16) float lwr[4096], lwi[4096];  // [i][o]
  __shared__ __align__(16) float lxr[1024], lxi[1024];  // [b][i]
  const int kk = blockIdx.x;
  for (int t = threadIdx.x; t < 4096; t += 512) {
    lwr[t] = wtr[(size_t)kk * 4096 + t];
    lwi[t] = wti[(size_t)kk * 4096 + t];
  }
  for (int t = threadIdx.x; t < 1024; t += 512) {
    lxr[t] = xre[(size_t)kk * 1024 + t];
    lxi[t] = xim[(size_t)kk * 1024 + t];
  }
  __syncthreads();
  const int o  = threadIdx.x & 63;
  const int bq = threadIdx.x >> 6;              // 0..7
  float accr[2] = {0, 0}, acci[2] = {0, 0};
  for (int iq = 0; iq < 16; ++iq) {
    float xrv[2][4], xiv[2][4];
#pragma unroll
    for (int p = 0; p < 2; ++p) {
      const int b = bq * 2 + p;
      float4 vr = ((const float4*)lxr)[b * 16 + iq];
      float4 vi = ((const float4*)lxi)[b * 16 + iq];
      xrv[p][0] = vr.x; xrv[p][1] = vr.y; xrv[p][2] = vr.z; xrv[p][3] = vr.w;
      xiv[p][0] = vi.x; xiv[p][1] = vi.y; xiv[p][2] = vi.z; xiv[p][3] = vi.w;
    }
#pragma unroll
    for (int j = 0; j < 4; ++j) {
      const int i2 = iq * 4 + j;
      const float wr = lwr[i2 * 64 + o];
      const float wi = lwi[i2 * 64 + o];
#pragma unroll
      for (int p = 0; p < 2; ++p) {
        accr[p] = fmaf(xrv[p][j], wr, fmaf(-xiv[p][j], wi, accr[p]));
        acci[p] = fmaf(xrv[p][j], wi, fmaf(xiv[p][j], wr, acci[p]));
      }
    }
  }
#pragma unroll
  for (int p = 0; p < 2; ++p) {
    const int b = bq * 2 + p;
    ore[(size_t)kk * 1024 + b * 64 + o] = accr[p];
    oim[(size_t)kk * 1024 + b * 64 + o] = acci[p];
  }
}

// ---------------------------------------------------------------- K3: h-inverse -> T2[b][h][ky][o]
__global__ __launch_bounds__(256, 2) void k3_hidft(const float* __restrict__ ore,
                                                   const float* __restrict__ oim,
                                                   float* __restrict__ t2r,
                                                   float* __restrict__ t2i) {
  const int b = blockIdx.x >> 5, hq = blockIdx.x & 31;
  const int q = threadIdx.x >> 6, lane = threadIdx.x & 63;   // lane = o
  const int ky0 = q * 4;
  float sc[4], ss[4];
  {
    const int h0 = 4 * hq;
    float wr = 1.f, wi = 0.f;
    if (h0 & 4)  crotP_t<4>(wr, wi);
    if (h0 & 8)  crotP_t<8>(wr, wi);
    if (h0 & 16) crotP_t<16>(wr, wi);
    if (h0 & 32) crotP_t<32>(wr, wi);
    if (h0 & 64) crotP_t<64>(wr, wi);
    sc[0] = wr; ss[0] = wi;
    crotP_t<1>(wr, wi); sc[1] = wr; ss[1] = wi;
    crotP_t<1>(wr, wi); sc[2] = wr; ss[2] = wi;
    crotP_t<1>(wr, wi); sc[3] = wr; ss[3] = wi;
  }
  float Rr[4] = {1.f, 1.f, 1.f, 1.f}, Ri[4] = {0.f, 0.f, 0.f, 0.f};
  float tr[4][4], ti[4][4];
#pragma unroll
  for (int j = 0; j < 4; ++j)
#pragma unroll
    for (int k = 0; k < 4; ++k) { tr[j][k] = 0.f; ti[j][k] = 0.f; }
  const size_t obase = (size_t)b * NO + lane;
  for (int kx = 0; kx < 16; ++kx) {
    float orv[4], oiv[4];
#pragma unroll
    for (int k = 0; k < 4; ++k) {
      const size_t idx = (size_t)(kx * 16 + ky0 + k) * (NB * NO) + obase;
      orv[k] = ore[idx];
      oiv[k] = oim[idx];
    }
#pragma unroll
    for (int j = 0; j < 4; ++j)
#pragma unroll
      for (int k = 0; k < 4; ++k) {
        tr[j][k] = fmaf(orv[k], Rr[j], fmaf(-oiv[k], Ri[j], tr[j][k]));
        ti[j][k] = fmaf(orv[k], Ri[j], fmaf( oiv[k], Rr[j], ti[j][k]));
      }
#pragma unroll
    for (int j = 0; j < 4; ++j) {
      const float nr = fmaf(Rr[j], sc[j], -(Ri[j] * ss[j]));
      const float ni = fmaf(Rr[j], ss[j], Ri[j] * sc[j]);
      Rr[j] = nr; Ri[j] = ni;
    }
  }
#pragma unroll
  for (int j = 0; j < 4; ++j) {
    const int h = hq * 4 + j;
#pragma unroll
    for (int k = 0; k < 4; ++k) {
      const int ky = ky0 + k;
      const float scale = (ky == 0 ? 1.0f : 2.0f) * (1.0f / 16384.0f);
      const size_t idx = ((size_t)(b * NH + h) * NM + ky) * NO + lane;
      t2r[idx] = tr[j][k] * scale;
      t2i[idx] = ti[j][k] * scale;
    }
  }
}

// ---------------------------------------------------------------- K5 helpers
template<int KY>
__device__ __forceinline__ void k5_load(const float* pr, const float* pi,
                                        float (&Tr)[16], float (&Ti)[16]) {
  if constexpr (KY < 16) {
    Tr[KY] = pr[KY * NO];
    Ti[KY] = pi[KY * NO];
    k5_load<KY + 1>(pr, pi, Tr, Ti);
  }
}
template<int KY, int W0>
__device__ __forceinline__ void k5_u(const float (&Tr)[16], const float (&Ti)[16],
                                     float (&Ur)[8], float (&Ui)[8]) {
  if constexpr (KY < 16) {
    caccP_t<(KY * W0) & 127>(Tr[KY], Ti[KY], Ur[KY & 7], Ui[KY & 7]);
    k5_u<KY + 1, W0>(Tr, Ti, Ur, Ui);
  }
}
template<int P>
__device__ __forceinline__ void k5_uzero(float (&Ur)[8], float (&Ui)[8]) {
  if constexpr (P < 8) { Ur[P] = 0.f; Ui[P] = 0.f; k5_uzero<P + 1>(Ur, Ui); }
}
template<int W0, int W0END>
__device__ __forceinline__ void k5_w0(const float (&Tr)[16], const float (&Ti)[16],
                                      float* yp) {
  if constexpr (W0 < W0END) {
    float Ur[8], Ui[8];
    k5_uzero<0>(Ur, Ui);
    k5_u<0, W0>(Tr, Ti, Ur, Ui);
    const float A  = Ur[0], B = Ur[4];
    const float Cr = Ur[2] + Ur[6], Ci = Ui[2] - Ui[6];
    const float Dr = Ur[1] + Ur[7], Di = Ui[1] - Ui[7];
    const float Er = Ur[3] + Ur[5], Ei = Ui[3] - Ui[5];
    const float P = A + B, M = A - B;
    const float DE = Dr + Er, IE = Di - Ei;
    const float X1 = R2F * ((Dr - Di) - (Er + Ei));
    const float X3 = R2F * ((Dr + Di) - (Er - Ei));
    const float MmC = M - Ci, MpC = M + Ci, PpC = P + Cr, PmC = P - Cr;
    yp[(0 * 16 + W0) * NO] = PpC + DE;
    yp[(4 * 16 + W0) * NO] = PpC - DE;
    yp[(2 * 16 + W0) * NO] = PmC - IE;
    yp[(6 * 16 + W0) * NO] = PmC + IE;
    yp[(1 * 16 + W0) * NO] = MmC + X1;
    yp[(5 * 16 + W0) * NO] = MmC - X1;
    yp[(3 * 16 + W0) * NO] = MpC - X3;
    yp[(7 * 16 + W0) * NO] = MpC + X3;
    k5_w0<W0 + 1, W0END>(Tr, Ti, yp);
  }
}

// K5: y[b,h,w,o] = Re sum_ky T2[b][h][ky][o] e^{+2pi i ky w/128}
// 4 waves/block: (slab-in-block, w0-half). Grid 1024 -> 4 waves/SIMD.
__global__ __launch_bounds__(256, 4) void k5_widft(const float* __restrict__ t2r,
                                                   const float* __restrict__ t2i,
                                                   float* __restrict__ y) {
  const int wv   = threadIdx.x >> 6;
  const int lane = threadIdx.x & 63;            // o
  const int sq   = wv >> 1;
  const int half = wv & 1;
  const int slab = blockIdx.x * 2 + sq;         // b*128 + h
  const float* pr = t2r + (size_t)slab * (NM * NO) + lane;
  const float* pi = t2i + (size_t)slab * (NM * NO) + lane;
  float Tr[16], Ti[16];
  k5_load<0>(pr, pi, Tr, Ti);
  float* yp = y + (size_t)slab * (NW * NO) + lane;
  if (half == 0) k5_w0<0, 8>(Tr, Ti, yp);
  else           k5_w0<8, 16>(Tr, Ti, yp);
}

extern "C" void kernel_launch(void* const* d_in, const int* in_sizes, int n_in,
                              void* d_out, int out_size, void* d_ws, size_t ws_size,
                              hipStream_t stream) {
  const float* x   = (const float*)d_in[0];
  const float* wre = (const float*)d_in[1];
  const float* wim = (const float*)d_in[2];
  float* ws  = (float*)d_ws;
  float* wtr = ws + OFF_WTR;
  float* wti = ws + OFF_WTI;
  float* ar  = ws + OFF_AR;   // T1, later T2 (re)
  float* ai  = ws + OFF_AI;   // T1, later T2 (im)
  float* xr  = ws + OFF_XR;
  float* xi  = ws + OFF_XI;
  float* orr = ws + OFF_OR;
  float* oii = ws + OFF_OI;
  float* y   = (float*)d_out;

  k_wt<<<128, 256, 0, stream>>>(wre, wim, wtr, wti);
  k1_wdft<<<1024, 256, 0, stream>>>(x, ar, ai);
  k2a_hdft<<<NB * NM, 1024, 0, stream>>>(ar, ai, xr, xi);
  k2b_mix<<<NM * NM, 512, 0, stream>>>(xr, xi, wtr, wti, orr, oii);
  k3_hidft<<<512, 256, 0, stream>>>(orr, oii, ar, ai);   // ar/ai now hold T2[b][h][ky][o]
  k5_widft<<<1024, 256, 0, stream>>>(ar, ai, y);
}